// Round 1
// baseline (187.093 us; speedup 1.0000x reference)
//
#include <hip/hip_runtime.h>
#include <stdint.h>

#define C_CH 192
#define HW   4096
#define NB   16
#define NO   5
#define LDSTRIDE 40   // shorts per LDS row: 32 + 8 pad (80 B) -> 4-way instead of 16-way conflicts

typedef __attribute__((ext_vector_type(8)))  short short8;
typedef __attribute__((ext_vector_type(16))) float floatx16;

__device__ __forceinline__ unsigned short f2bf(float f) {
    unsigned int u = __float_as_uint(f);
    unsigned int r = (u + 0x7fffu + ((u >> 16) & 1u)) >> 16;  // RNE truncate to bf16
    return (unsigned short)r;
}

// ---------------- Kernel 1: fp32 -> bf16 ----------------
__global__ __launch_bounds__(256) void convert_kernel(const float* __restrict__ x,
                                                      unsigned short* __restrict__ xb,
                                                      int n8) {
    int i = blockIdx.x * 256 + threadIdx.x;
    if (i >= n8) return;
    const float4* p = (const float4*)(x) + (size_t)i * 2;
    float4 v0 = p[0], v1 = p[1];
    ushort4 o0, o1;
    o0.x = f2bf(v0.x); o0.y = f2bf(v0.y); o0.z = f2bf(v0.z); o0.w = f2bf(v0.w);
    o1.x = f2bf(v1.x); o1.y = f2bf(v1.y); o1.z = f2bf(v1.z); o1.w = f2bf(v1.w);
    ushort4* q = (ushort4*)(xb) + (size_t)i * 2;
    q[0] = o0; q[1] = o1;
}

// ---------------- Kernel 2: 80 x (192x192x4096) bf16 MFMA GEMM ----------------
// grid = 720 blocks: (16 batches x 5 offsets x 9 tiles of 64x64)
// block = 256 thr (4 waves). Split-K: wave w owns spatial rows [16w,16w+16),
// private LDS (no barriers in main loop), 2x2 of v_mfma_f32_32x32x16_bf16.
__global__ __launch_bounds__(256) void cofe_gemm(const unsigned short* __restrict__ xb,
                                                 float* __restrict__ out) {
    int blk = blockIdx.x;
    // XCD swizzle: 720 = 8 * 90; same-batch blocks land on the same XCD for L2 locality
    int work = (blk & 7) * 90 + (blk >> 3);
    int b  = work / 45;
    int r  = work % 45;
    int o  = r / 9;
    int t  = r % 9;
    int ti = t / 3, tj = t % 3;
    const int dyA[5] = {-1, -1, -1, 0, 0};
    const int dxA[5] = {-1,  0,  1, -1, 0};
    int dy = dyA[o], dx = dxA[o];
    int c0 = ti * 64, d0 = tj * 64;

    __shared__ char smem[40960];
    int wv   = threadIdx.x >> 6;
    int lane = threadIdx.x & 63;
    unsigned short* As = (unsigned short*)(smem + wv * 10240);
    unsigned short* Bs = As + 64 * LDSTRIDE;

    const unsigned short* Abase = xb + ((size_t)(b * C_CH + c0)) * HW;
    const unsigned short* Bbase = xb + ((size_t)(b * C_CH + d0)) * HW;

    floatx16 acc[2][2];
    #pragma unroll
    for (int im = 0; im < 2; ++im)
        #pragma unroll
        for (int jn = 0; jn < 2; ++jn)
            #pragma unroll
            for (int e = 0; e < 16; ++e)
                acc[im][jn][e] = 0.0f;

    int lr = lane & 31;   // row within 32-tile
    int lo = lane >> 5;   // k-octet selector

    for (int s = 0; s < 32; ++s) {
        int h    = wv * 16 + (s >> 1);
        int half = s & 1;
        int k0e  = half * 32;    // element offset within the spatial row

        // ---- stage A (center): 64 rows x 32 k, contiguous ----
        const unsigned short* Ag = Abase + h * 64 + k0e;
        #pragma unroll
        for (int i = 0; i < 4; ++i) {
            int c    = i * 64 + lane;
            int rr   = c >> 2, part = c & 3;
            uint4 v = *(const uint4*)(Ag + (size_t)rr * HW + part * 8);
            *(uint4*)(As + rr * LDSTRIDE + part * 8) = v;
        }

        // ---- stage B (shifted): dy via row select, dx via register funnel shift ----
        int hp = h + dy; if (hp < 0) hp = 0;
        const unsigned short* Bg = Bbase + hp * 64;
        #pragma unroll
        for (int j = 0; j < 4; ++j) {
            int gi = j * 64 + lane;
            int rr = gi >> 2, g = gi & 3;
            const unsigned short* rowp = Bg + (size_t)rr * HW;
            int e0 = k0e + g * 8;
            uint4 v = *(const uint4*)(rowp + e0);
            if (dx == 1) {
                unsigned int ex = rowp[(e0 + 8 < 64) ? (e0 + 8) : 63];
                uint4 w;
                w.x = (v.x >> 16) | (v.y << 16);
                w.y = (v.y >> 16) | (v.z << 16);
                w.z = (v.z >> 16) | (v.w << 16);
                w.w = (v.w >> 16) | (ex << 16);
                v = w;
            } else if (dx == -1) {
                unsigned int ex = rowp[e0 > 0 ? e0 - 1 : 0];
                uint4 w;
                w.x = ex        | (v.x << 16);
                w.y = (v.x >> 16) | (v.y << 16);
                w.z = (v.y >> 16) | (v.z << 16);
                w.w = (v.z >> 16) | (v.w << 16);
                v = w;
            }
            *(uint4*)(Bs + rr * LDSTRIDE + g * 8) = v;
        }

        // ---- compute: 2 k-steps x 2x2 MFMA ----
        #pragma unroll
        for (int kk = 0; kk < 2; ++kk) {
            int ko = kk * 16 + lo * 8;
            short8 a0 = *(const short8*)(As + lr * LDSTRIDE + ko);
            short8 a1 = *(const short8*)(As + (lr + 32) * LDSTRIDE + ko);
            short8 b0 = *(const short8*)(Bs + lr * LDSTRIDE + ko);
            short8 b1 = *(const short8*)(Bs + (lr + 32) * LDSTRIDE + ko);
            acc[0][0] = __builtin_amdgcn_mfma_f32_32x32x16_bf16(a0, b0, acc[0][0], 0, 0, 0);
            acc[0][1] = __builtin_amdgcn_mfma_f32_32x32x16_bf16(a0, b1, acc[0][1], 0, 0, 0);
            acc[1][0] = __builtin_amdgcn_mfma_f32_32x32x16_bf16(a1, b0, acc[1][0], 0, 0, 0);
            acc[1][1] = __builtin_amdgcn_mfma_f32_32x32x16_bf16(a1, b1, acc[1][1], 0, 0, 0);
        }
    }

    // ---- epilogue: reduce 4 split-K partials via LDS, store raw co ----
    __syncthreads();
    float* red = (float*)smem;
    size_t obase = ((size_t)(b * NO + o)) * (C_CH * C_CH);
    #pragma unroll
    for (int tt = 0; tt < 2; ++tt) {
        #pragma unroll
        for (int jn = 0; jn < 2; ++jn) {
            #pragma unroll
            for (int reg = 0; reg < 16; ++reg) {
                int row = (reg & 3) + 8 * (reg >> 2) + 4 * lo;  // C/D layout (m74/m101)
                int col = jn * 32 + lr;
                red[wv * 2048 + row * 64 + col] = acc[tt][jn][reg];
            }
        }
        __syncthreads();
        for (int e = threadIdx.x; e < 2048; e += 256) {
            float sum = red[e] + red[2048 + e] + red[4096 + e] + red[6144 + e];
            int c = c0 + tt * 32 + (e >> 6);
            int d = d0 + (e & 63);
            out[obase + (size_t)c * C_CH + d] = sum;
        }
        __syncthreads();
    }
}

// ---------------- Kernel 3: per-(b,o) L2 normalization, in place ----------------
__global__ __launch_bounds__(256) void normalize_kernel(float* __restrict__ out) {
    int bo = blockIdx.x;  // 80
    float* p = out + (size_t)bo * (C_CH * C_CH);
    float s = 0.f;
    for (int i = threadIdx.x * 4; i < C_CH * C_CH; i += 1024) {
        float4 v = *(const float4*)(p + i);
        s += v.x * v.x + v.y * v.y + v.z * v.z + v.w * v.w;
    }
    #pragma unroll
    for (int off = 32; off > 0; off >>= 1) s += __shfl_down(s, off, 64);
    __shared__ float wsum[4];
    __shared__ float inv_s;
    int wv = threadIdx.x >> 6, lane = threadIdx.x & 63;
    if (lane == 0) wsum[wv] = s;
    __syncthreads();
    if (threadIdx.x == 0) {
        float nrm = sqrtf(wsum[0] + wsum[1] + wsum[2] + wsum[3]);
        inv_s = 1.0f / fmaxf(nrm, 1e-12f);
    }
    __syncthreads();
    float inv = inv_s;
    for (int i = threadIdx.x * 4; i < C_CH * C_CH; i += 1024) {
        float4 v = *(const float4*)(p + i);
        v.x *= inv; v.y *= inv; v.z *= inv; v.w *= inv;
        *(float4*)(p + i) = v;
    }
}

extern "C" void kernel_launch(void* const* d_in, const int* in_sizes, int n_in,
                              void* d_out, int out_size, void* d_ws, size_t ws_size,
                              hipStream_t stream) {
    const float* x = (const float*)d_in[0];
    float* out = (float*)d_out;
    unsigned short* xb = (unsigned short*)d_ws;   // 25,165,824 B of bf16 scratch

    int total = NB * C_CH * HW;   // 12,582,912
    int n8 = total / 8;           // 1,572,864 -> 6144 blocks exactly

    convert_kernel<<<n8 / 256, 256, 0, stream>>>(x, xb, n8);
    cofe_gemm<<<720, 256, 0, stream>>>(xb, out);
    normalize_kernel<<<80, 256, 0, stream>>>(out);
}